// Round 8
// baseline (165.015 us; speedup 1.0000x reference)
//
#include <hip/hip_runtime.h>
#include <cmath>

#define A_CNT 196416
#define C_CNT 90
#define CLS_BYTES (196416u * 90u * 4u)   // 70,709,760
#define NWI2 (A_CNT / 8)                 // 24552 wave-iters (2 quads = 8 anchors each)
#define TOPK 100u
#define CAPB 2048
#define NB_RED 1280                      // 5 blocks/CU (LDS-gated) -> 20 waves/CU
#define NWAVES 5120                      // 5 rolling slots/wave (25600 >= 24552)
#define NB_GAT 192

// ws layout (bytes):
//   [0, 785664)          keys[A]   (uint32 monotonic score keys; 0 = below threshold)
//   [785664, 789760)     hist1[1024] (coarse: idx 0 = zero-key, 1..565 = top16-0x3D4B)
//   [789760, 789824)     ctrl[16]: 0=binB(top16) 1=G 5=candA_cnt 6=candB_cnt 8=doneR 9=doneG
//   [789824, 790336)     candA[128]  (keys strictly above binB; count = G < 100)
//   [790336, 798528)     candB[2048] (keys with top16 == binB)
#define OFF_HIST1 785664u
#define OFF_CTRL  789760u
#define OFF_CANDA 789824u
#define OFF_CANDB 790336u

#define AGENT_LD(p)    __hip_atomic_load((p), __ATOMIC_RELAXED, __HIP_MEMORY_SCOPE_AGENT)
#define AGENT_ST(p, v) __hip_atomic_store((p), (v), __ATOMIC_RELAXED, __HIP_MEMORY_SCOPE_AGENT)

// ---- R13: global_load_lds staging, 20 waves/CU -----------------------------
// R12's asm register pipeline (12-13 loads provably in flight) did NOT move
// the ~2.5 TB/s plateau -> MLP alone is not the limiter; the exposed per-wave
// serial phase (shfl chain + sigmoid) at 8-12 waves/CU is. global_load_lds
// staging has ZERO VGPR cost -> occupancy is LDS-gated only: 28 KB/block = 5
// blocks/CU = 20 waves/CU, depth-2 rolling, wave-private buffers (no barrier,
// no vmcnt(0) drain mid-loop). Wave-iter = 2 quads = 8 anchors = 2880 B =
// 3 DMA instructions; 16-lane group per anchor PAIR (720 B, 16-B aligned;
// straddle float4 j=22 splits x,y|z,w across the pair). vmcnt: 3 per stage,
// +1 per reduce (uint2 keys store); waits 3,4,4,4,1 - never 0 mid-loop.

typedef __attribute__((address_space(1))) const void* gas_t;
typedef __attribute__((address_space(3))) void* las_t;

#define STAGE(B, wi)                                                        \
    {                                                                       \
        asm volatile("s_waitcnt lgkmcnt(0)" ::: "memory");                  \
        const char* gb_ = clsb + (size_t)(wi) * 2880 + lane * 16;           \
        const char* g2_ = gb_ + 2048;                                       \
        if (g2_ > clsend16) g2_ = clsend16;    /* tail clamp, dup harmless */ \
        __builtin_amdgcn_global_load_lds((gas_t)gb_,          (las_t)(B),          16, 0, 0); \
        __builtin_amdgcn_global_load_lds((gas_t)(gb_ + 1024), (las_t)((B) + 1024), 16, 0, 0); \
        __builtin_amdgcn_global_load_lds((gas_t)g2_,          (las_t)((B) + 2048), 16, 0, 0); \
    }                                                                       \
    __builtin_amdgcn_sched_barrier(0);

#define WAITV(N)                                                            \
    asm volatile("s_waitcnt vmcnt(" #N ")" ::: "memory");                   \
    __builtin_amdgcn_sched_barrier(0);

#define FMAX4(v) fmaxf(fmaxf((v).x, (v).y), fmaxf((v).z, (v).w))

// 16-lane group g owns anchor pair P = wi*4+g (anchors 2P, 2P+1), 45 float4
// at LDS byte g*720. Lane s reads j = s, s+16, s+32 (j<45); j=22 straddles.
#define REDUCE_EMIT(B, wi)                                                  \
    {                                                                       \
        const float4* q_ = (const float4*)((B) + g * 720);                  \
        const float4 v0_ = q_[s];                                           \
        const float4 v1_ = q_[s + 16];                                      \
        const float4 v2_ = q_[(s < 13) ? (s + 32) : s];                     \
        float m0 = FMAX4(v0_);                       /* j in [0,15]: anchor0 */ \
        float m1 = -INFINITY;                                               \
        {                                                                   \
            const float a01 = fmaxf(v1_.x, v1_.y), a23 = fmaxf(v1_.z, v1_.w); \
            if (s < 6)       m0 = fmaxf(m0, fmaxf(a01, a23));               \
            else if (s == 6) { m0 = fmaxf(m0, a01); m1 = a23; }             \
            else             m1 = fmaxf(a01, a23);                          \
        }                                                                   \
        if (s < 13) m1 = fmaxf(m1, FMAX4(v2_));      /* j in [32,44] */     \
        _Pragma("unroll")                                                   \
        for (int d_ = 1; d_ < 16; d_ <<= 1) {                               \
            m0 = fmaxf(m0, __shfl_xor(m0, d_));                             \
            m1 = fmaxf(m1, __shfl_xor(m1, d_));                             \
        }                                                                   \
        if (s == 0) {                                                       \
            float p0 = 1.0f / (1.0f + expf(-m0));   /* sigmoid(max)==max(sigmoid) */ \
            float p1 = 1.0f / (1.0f + expf(-m1));                           \
            unsigned k0 = (p0 > 0.05f) ? __float_as_uint(p0) : 0u;          \
            unsigned k1 = (p1 > 0.05f) ? __float_as_uint(p1) : 0u;          \
            *(uint2*)(keys + 2 * ((size_t)(wi) * 4 + g)) = make_uint2(k0, k1); \
            unsigned h0 = k0 ? (min(k0 >> 16, 0x3F80u) - 0x3D4Bu) : 0u;     \
            unsigned h1 = k1 ? (min(k1 >> 16, 0x3F80u) - 0x3D4Bu) : 0u;     \
            atomicAdd(&lhist[h0], 1u);                                      \
            atomicAdd(&lhist[h1], 1u);                                      \
        }                                                                   \
    }

#define SUFFIX_SCAN_SDATA()                                                 \
    for (int d_ = 1; d_ < 256; d_ <<= 1) {                                  \
        __syncthreads();                                                    \
        unsigned add_ = (t + d_ < 256) ? sdata[t + d_] : 0u;                \
        __syncthreads();                                                    \
        sdata[t] += add_;                                                   \
    }                                                                       \
    __syncthreads();

__global__ __launch_bounds__(256) void k_reduce(const float* __restrict__ cls,
                                                unsigned* __restrict__ keys,
                                                unsigned* __restrict__ hist1,
                                                unsigned* __restrict__ ctrl) {
    __shared__ __align__(16) char stg[4][2][3072];   // 24.5 KB wave-private dbuf
    __shared__ unsigned lhist[576];
    __shared__ unsigned sdata[256];
    __shared__ unsigned sbin[2];
    __shared__ int sflag;
    const int t = threadIdx.x;
    for (int j = t; j < 576; j += 256) lhist[j] = 0u;
    __syncthreads();

    const int lane = t & 63;
    const int g = lane >> 4, s = lane & 15;      // 4 groups of 16 lanes
    const int wv = t >> 6;
    const int w = blockIdx.x * 4 + wv;           // wave id in [0, 5120)
    const char* clsb = (const char*)cls;
    const char* clsend16 = clsb + (CLS_BYTES - 16u);
    char* b0 = &stg[wv][0][0];
    char* b1 = &stg[wv][1][0];

    // wave w owns wave-iters {w + 5120k, k=0..4} ∩ [0, 24552) — exact cover.
    const int wi0 = w;
    const int wi1 = w + NWAVES;
    const int wi2 = w + 2 * NWAVES;
    const int wi3 = w + 3 * NWAVES;              // < 20480 < 24552, always valid
    const int wi4 = w + 4 * NWAVES;
    const bool has4 = (wi4 < NWI2);              // w < 4072
    const int wi4c = has4 ? wi4 : wi0;           // clamped stage target; emit guarded

    STAGE(b0, wi0);                              // 3 DMAs in flight
    STAGE(b1, wi1);                              // 6
    WAITV(3)                                     // b0 ready
    REDUCE_EMIT(b0, wi0);                        // +store
    STAGE(b0, wi2);
    WAITV(4)                                     // b1 ready (store + 3 outstanding)
    REDUCE_EMIT(b1, wi1);
    STAGE(b1, wi3);
    WAITV(4)                                     // b0(wi2) ready
    REDUCE_EMIT(b0, wi2);
    STAGE(b0, wi4c);
    WAITV(4)                                     // b1(wi3) ready
    REDUCE_EMIT(b1, wi3);
    WAITV(1)                                     // b0(wi4) ready
    if (has4) REDUCE_EMIT(b0, wi4);

    __syncthreads();
    for (int j = t; j < 576; j += 256) {
        unsigned c = lhist[j];
        if (c) atomicAdd(&hist1[j], c);
    }
    __syncthreads();                             // drains each thread's atomics (vmcnt)
    if (t == 0) sflag = (atomicAdd(&ctrl[8], 1u) == NB_RED - 1u) ? 1 : 0;
    __syncthreads();
    if (!sflag) return;

    // ---- fused k_scan (last block only; uniform branch, barriers legal) ----
    const unsigned target = TOPK;
    unsigned ssum = 0;
#pragma unroll
    for (int j = 0; j < 4; ++j) ssum += AGENT_LD(&hist1[t * 4 + j]);
    sdata[t] = ssum;
    SUFFIX_SCAN_SDATA()
    {
        unsigned mysuf  = sdata[t];
        unsigned nxtsuf = (t < 255) ? sdata[t + 1] : 0u;
        if (nxtsuf < target && mysuf >= target) { sbin[0] = (unsigned)t; sbin[1] = nxtsuf; }
    }
    __syncthreads();
    const unsigned chunkB = sbin[0];
    const unsigned gAbove = sbin[1];
    sdata[t] = (t < 4) ? AGENT_LD(&hist1[chunkB * 4 + t]) : 0u;
    SUFFIX_SCAN_SDATA()
    {
        unsigned mysuf  = sdata[t] + gAbove;
        unsigned nxtsuf = ((t < 255) ? sdata[t + 1] : 0u) + gAbove;
        if (nxtsuf < target && mysuf >= target) {
            unsigned bin = chunkB * 4 + (unsigned)t;  // hist index: 0=zeros, 1..565
            ctrl[0] = bin ? (bin + 0x3D4Bu) : 0u;     // true top-16 bits
            ctrl[1] = nxtsuf;                         // G < 100
        }
    }
}

// Kernel 2: gather candidates (one uint4 pass over keys), then the LAST block
// runs the full ranking (byte-refined, R9-validated) + argmax + box decode.
__global__ __launch_bounds__(256) void k_gather(const float* __restrict__ cls,
                                                const float* __restrict__ reg,
                                                const float* __restrict__ anc,
                                                const unsigned* __restrict__ keys,
                                                unsigned* __restrict__ ctrl,
                                                unsigned* __restrict__ candA,
                                                unsigned* __restrict__ candB,
                                                float* __restrict__ out) {
    __shared__ unsigned sAi[128], sAk[128];
    __shared__ unsigned sBi[CAPB], sBk[CAPB];
    __shared__ unsigned sdata[256];
    __shared__ unsigned sbin[2];
    __shared__ unsigned sel[TOPK];
    __shared__ int sflag;
    const int t = threadIdx.x;

    const unsigned binB = ctrl[0];               // prev kernel -> plain load ok
    const int i4 = blockIdx.x * 256 + t;
    if (i4 < A_CNT / 4) {
        uint4 k = ((const uint4*)keys)[i4];
        const unsigned base = (unsigned)(4 * i4);
#pragma unroll
        for (int j = 0; j < 4; ++j) {
            unsigned kk = (j == 0) ? k.x : (j == 1) ? k.y : (j == 2) ? k.z : k.w;
            unsigned t16 = kk >> 16;
            if (t16 > binB) {
                unsigned q = atomicAdd(&ctrl[5], 1u);
                if (q < 128u) AGENT_ST(&candA[q], base + j);
            } else if (t16 == binB) {
                unsigned q = atomicAdd(&ctrl[6], 1u);
                if (q < (unsigned)CAPB) AGENT_ST(&candB[q], base + j);
            }
        }
    }
    __syncthreads();                             // drains this thread's stores/atomics
    if (t == 0) sflag = (atomicAdd(&ctrl[9], 1u) == (unsigned)NB_GAT - 1u) ? 1 : 0;
    __syncthreads();
    if (!sflag) return;

    // ---- fused k_final (last block only) ----
    const unsigned nA = min(AGENT_LD(&ctrl[5]), 128u);   // exact G < 100
    const unsigned nB = min(AGENT_LD(&ctrl[6]), (unsigned)CAPB);
    const unsigned need = TOPK - nA;                     // >= 1; in-bin count >= need

    if (t < (int)nA) { unsigned i = AGENT_LD(&candA[t]); sAi[t] = i; sAk[t] = keys[i]; }
    for (unsigned e = (unsigned)t; e < nB; e += 256u) {
        unsigned i = AGENT_LD(&candB[e]); sBi[e] = i; sBk[e] = keys[i];
    }
    sdata[t] = 0u;
    __syncthreads();
    // byte-refinement histogram over key bits [15:8] (all candB share top16,
    // so within the bin byte order == key order).
    for (unsigned e = (unsigned)t; e < nB; e += 256u)
        atomicAdd(&sdata[(sBk[e] >> 8) & 0xFFu], 1u);
    SUFFIX_SCAN_SDATA()
    {
        unsigned mysuf  = sdata[t];
        unsigned nxtsuf = (t < 255) ? sdata[t + 1] : 0u;
        if (nxtsuf < need && mysuf >= need) { sbin[0] = (unsigned)t; sbin[1] = nxtsuf; }
    }
    __syncthreads();
    const unsigned bstar = sbin[0];              // boundary byte
    const unsigned S1    = sbin[1];              // count with byte > bstar (< need)

    if (t < (int)nA) {                           // rank strictly-above candidates
        unsigned mi = sAi[t], mk = sAk[t], r = 0;
        for (unsigned j = 0; j < nA; ++j) {
            unsigned ok = sAk[j];
            if (ok > mk || (ok == mk && sAi[j] < mi)) r++;
        }
        sel[r] = mi;
    }
    // in-bin: byte>bstar all selected (subset rank == global in-bin rank);
    // byte==bstar: best (need-S1) selected; byte<bstar: no inner scan at all.
    for (unsigned e = (unsigned)t; e < nB; e += 256u) {
        unsigned mk = sBk[e], mi = sBi[e];
        unsigned mb = (mk >> 8) & 0xFFu;
        if (mb > bstar) {
            unsigned r = 0;
            for (unsigned j = 0; j < nB; ++j) {
                unsigned ok = sBk[j];
                if (((ok >> 8) & 0xFFu) > bstar &&
                    (ok > mk || (ok == mk && sBi[j] < mi))) r++;
            }
            sel[nA + r] = mi;
        } else if (mb == bstar) {
            unsigned r = 0;
            for (unsigned j = 0; j < nB; ++j) {
                unsigned ok = sBk[j];
                if (((ok >> 8) & 0xFFu) == bstar &&
                    (ok > mk || (ok == mk && sBi[j] < mi))) r++;
            }
            if (r < need - S1) sel[nA + S1 + r] = mi;
        }
    }
    __syncthreads();

    if (t < (int)TOPK) {
        const unsigned a = sel[t];
        const float2* __restrict__ row = (const float2*)(cls + (size_t)a * C_CNT);
        float2 vr[45];
#pragma unroll
        for (int c = 0; c < 45; ++c) vr[c] = row[c]; // issue all 45 loads up front
        float bv = -INFINITY; int bi = 0;
#pragma unroll
        for (int c = 0; c < 45; ++c) {               // argmax over RAW logits (sigmoid
            if (vr[c].x > bv) { bv = vr[c].x; bi = 2 * c; }      // monotonic; strict > =
            if (vr[c].y > bv) { bv = vr[c].y; bi = 2 * c + 1; }  // first-index semantics)
        }
        float score = __uint_as_float(keys[a]);      // prob bits, or 0.0 if thresholded
        const float4 an = ((const float4*)anc)[a];
        const float4 rg = ((const float4*)reg)[a];
        float wa = an.z - an.x, ha = an.w - an.y;
        float cxa = an.x + 0.5f * wa, cya = an.y + 0.5f * ha;
        float dx = rg.x * 0.1f, dy = rg.y * 0.1f;
        float dw = rg.z * 0.2f, dh = rg.w * 0.2f;
        float cx = cxa + dx * wa, cy = cya + dy * ha;
        float w2 = expf(dw) * wa, h2 = expf(dh) * ha;
        out[t * 4 + 0] = fmaxf(cx - 0.5f * w2, 0.0f);
        out[t * 4 + 1] = fmaxf(cy - 0.5f * h2, 0.0f);
        out[t * 4 + 2] = fminf(cx + 0.5f * w2, 1024.0f);
        out[t * 4 + 3] = fminf(cy + 0.5f * h2, 1024.0f);
        out[400 + t] = score;
        out[500 + t] = (float)bi;
    }
}

extern "C" void kernel_launch(void* const* d_in, const int* in_sizes, int n_in,
                              void* d_out, int out_size, void* d_ws, size_t ws_size,
                              hipStream_t stream) {
    const float* reg = (const float*)d_in[1];
    const float* cls = (const float*)d_in[2];
    const float* anc = (const float*)d_in[3];
    float* out = (float*)d_out;
    char* ws = (char*)d_ws;
    unsigned* keys  = (unsigned*)ws;
    unsigned* hist1 = (unsigned*)(ws + OFF_HIST1);
    unsigned* ctrl  = (unsigned*)(ws + OFF_CTRL);
    unsigned* candA = (unsigned*)(ws + OFF_CANDA);
    unsigned* candB = (unsigned*)(ws + OFF_CANDB);

    // hist1 (4 KB) + ctrl (64 B, incl. done counters) are contiguous.
    hipMemsetAsync(hist1, 0, 4096 + 64, stream);
    k_reduce<<<NB_RED, 256, 0, stream>>>(cls, keys, hist1, ctrl);
    k_gather<<<NB_GAT, 256, 0, stream>>>(cls, reg, anc, keys, ctrl, candA, candB, out);
}

// Round 9
// 151.384 us; speedup vs baseline: 1.0900x; 1.0900x over previous
//
#include <hip/hip_runtime.h>
#include <cmath>

#define A_CNT 196416
#define C_CNT 90
#define QUADS (A_CNT / 4)            // 49104 quads (4 anchors = 1440 B each)
#define QITERS (QUADS / 8)           // 6138 wave-iterations (8 quads per wave-iter)
#define TOPK 100u
#define CAPB 2048
#define NB_RED 512                   // 2 blocks/CU, fully resident, 2048 waves
#define NWAVES 2048                  // grid-stride in wave-iters
#define NB_GAT 192

// ws layout (bytes):
//   [0, 785664)          keys[A]   (uint32 monotonic score keys; 0 = below threshold)
//   [785664, 789760)     hist1[1024] (coarse: idx 0 = zero-key, 1..565 = top16-0x3D4B)
//   [789760, 789824)     ctrl[16]: 0=binB(top16) 1=G 5=candA_cnt 6=candB_cnt 8=doneR 9=doneG
//   [789824, 790336)     candA[128]  (keys strictly above binB; count = G < 100)
//   [790336, 798528)     candB[2048] (keys with top16 == binB)
#define OFF_HIST1 785664u
#define OFF_CTRL  789760u
#define OFF_CANDA 789824u
#define OFF_CANDB 790336u

#define AGENT_LD(p)    __hip_atomic_load((p), __ATOMIC_RELAXED, __HIP_MEMORY_SCOPE_AGENT)
#define AGENT_ST(p, v) __hip_atomic_store((p), (v), __ATOMIC_RELAXED, __HIP_MEMORY_SCOPE_AGENT)

// ---- R14: convergence build -----------------------------------------------
// k_reduce = R7 verbatim (best measured: 133.9 total; rolling depth-2 source
// pipeline, 8 waves/CU, L,L,R,L,R,R). The R9/R11/R12/R13 ladder showed three
// mechanistically different deeper/wider pipelines all pin at 1.5-2.1 TB/s
// logical read -> per-CU consumption-path cap, not MLP/TLP/source-BW.
// k_gather = byte-refined in-bin ranking (bits 15:8 histogram + suffix scan;
// hardware-validated absmax=0 in the R9 and R13 runs) -> caps the quadratic
// at ~need^2 instead of nB^2.

#define LOADQ(V, qq)                                                        \
    {                                                                       \
        const float4* __restrict__ r4_ = cls4 + (size_t)(qq) * 90;          \
        _Pragma("unroll")                                                   \
        for (int i_ = 0; i_ < 12; ++i_) {                                   \
            const int j_ = s + 8 * i_;                                      \
            V[i_] = r4_[(j_ < 90) ? j_ : 89];  /* clamp dup; masked below */ \
        }                                                                   \
    }                                                                       \
    __builtin_amdgcn_sched_barrier(0);

// Quad anchors a0..a3 at float offsets 0/90/180/270 within the 360-float quad;
// straddle chunks: j=22 (88,89|90,91) and j=67 (268,269|270,271).
#define REDUCE_EMIT(V, qq)                                                  \
    {                                                                       \
        float m0 = -INFINITY, m1 = -INFINITY, m2 = -INFINITY, m3 = -INFINITY; \
        _Pragma("unroll")                                                   \
        for (int i_ = 0; i_ < 12; ++i_) {                                   \
            const int j_ = s + 8 * i_;                                      \
            const float4 vv = V[i_];                                        \
            const float a01 = fmaxf(vv.x, vv.y), a23 = fmaxf(vv.z, vv.w);   \
            const float all = fmaxf(a01, a23);                              \
            if (j_ < 22)       m0 = fmaxf(m0, all);                         \
            else if (j_ == 22) { m0 = fmaxf(m0, a01); m1 = fmaxf(m1, a23); }\
            else if (j_ < 45)  m1 = fmaxf(m1, all);                         \
            else if (j_ < 67)  m2 = fmaxf(m2, all);                         \
            else if (j_ == 67) { m2 = fmaxf(m2, a01); m3 = fmaxf(m3, a23); }\
            else if (j_ < 90)  m3 = fmaxf(m3, all);                         \
        }                                                                   \
        _Pragma("unroll")                                                   \
        for (int d_ = 1; d_ < 8; d_ <<= 1) {                                \
            m0 = fmaxf(m0, __shfl_xor(m0, d_));                             \
            m1 = fmaxf(m1, __shfl_xor(m1, d_));                             \
            m2 = fmaxf(m2, __shfl_xor(m2, d_));                             \
            m3 = fmaxf(m3, __shfl_xor(m3, d_));                             \
        }                                                                   \
        if (s == 0) {                                                       \
            float p0 = 1.0f / (1.0f + expf(-m0));   /* sigmoid(max)==max(sigmoid) */ \
            float p1 = 1.0f / (1.0f + expf(-m1));                           \
            float p2 = 1.0f / (1.0f + expf(-m2));                           \
            float p3 = 1.0f / (1.0f + expf(-m3));                           \
            unsigned k0 = (p0 > 0.05f) ? __float_as_uint(p0) : 0u;          \
            unsigned k1 = (p1 > 0.05f) ? __float_as_uint(p1) : 0u;          \
            unsigned k2 = (p2 > 0.05f) ? __float_as_uint(p2) : 0u;          \
            unsigned k3 = (p3 > 0.05f) ? __float_as_uint(p3) : 0u;          \
            *(uint4*)(keys + 4 * (size_t)(qq)) = make_uint4(k0, k1, k2, k3);\
            unsigned h0 = k0 ? (min(k0 >> 16, 0x3F80u) - 0x3D4Bu) : 0u;     \
            unsigned h1 = k1 ? (min(k1 >> 16, 0x3F80u) - 0x3D4Bu) : 0u;     \
            unsigned h2 = k2 ? (min(k2 >> 16, 0x3F80u) - 0x3D4Bu) : 0u;     \
            unsigned h3 = k3 ? (min(k3 >> 16, 0x3F80u) - 0x3D4Bu) : 0u;     \
            atomicAdd(&lhist[h0], 1u);                                      \
            atomicAdd(&lhist[h1], 1u);                                      \
            atomicAdd(&lhist[h2], 1u);                                      \
            atomicAdd(&lhist[h3], 1u);                                      \
        }                                                                   \
    }

#define SUFFIX_SCAN_SDATA()                                                 \
    for (int d_ = 1; d_ < 256; d_ <<= 1) {                                  \
        __syncthreads();                                                    \
        unsigned add_ = (t + d_ < 256) ? sdata[t + d_] : 0u;                \
        __syncthreads();                                                    \
        sdata[t] += add_;                                                   \
    }                                                                       \
    __syncthreads();

__global__ __launch_bounds__(256, 2) void k_reduce(const float* __restrict__ cls,
                                                   unsigned* __restrict__ keys,
                                                   unsigned* __restrict__ hist1,
                                                   unsigned* __restrict__ ctrl) {
    __shared__ unsigned lhist[576];
    __shared__ unsigned sdata[256];
    __shared__ unsigned sbin[2];
    __shared__ int sflag;
    const int t = threadIdx.x;
    for (int j = t; j < 576; j += 256) lhist[j] = 0u;
    __syncthreads();

    const int lane = t & 63;
    const int g = lane >> 3, s = lane & 7;
    const int w = blockIdx.x * 4 + (t >> 6);     // wave id in [0, 2048)
    const float4* __restrict__ cls4 = (const float4*)cls;

    // wave w owns iters {w, w+2048, w+4096} ∩ [0, 6138) — exact cover of QITERS.
    const int qi1 = w + NWAVES;                  // always < 6138
    const int qi2 = w + 2 * NWAVES;
    const bool has2 = (qi2 < QITERS);            // false only for 6 waves
    const int q0 = w * 8 + g;
    const int q1 = qi1 * 8 + g;
    const int q2 = (has2 ? qi2 : w) * 8 + g;     // clamped load target; emit guarded

    float4 vA[12], vB[12];
    LOADQ(vA, q0);                               // 12 loads in flight
    LOADQ(vB, q1);                               // 24 loads in flight
    REDUCE_EMIT(vA, q0);                         // waits A; vB stays in flight
    LOADQ(vA, q2);                               // refill while vB lands
    REDUCE_EMIT(vB, q1);
    if (has2) REDUCE_EMIT(vA, q2);

    __syncthreads();
    for (int j = t; j < 576; j += 256) {
        unsigned c = lhist[j];
        if (c) atomicAdd(&hist1[j], c);
    }
    __syncthreads();                             // drains each thread's atomics (vmcnt)
    if (t == 0) sflag = (atomicAdd(&ctrl[8], 1u) == NB_RED - 1u) ? 1 : 0;
    __syncthreads();
    if (!sflag) return;

    // ---- fused k_scan (last block only; uniform branch, barriers legal) ----
    const unsigned target = TOPK;
    unsigned ssum = 0;
#pragma unroll
    for (int j = 0; j < 4; ++j) ssum += AGENT_LD(&hist1[t * 4 + j]);
    sdata[t] = ssum;
    SUFFIX_SCAN_SDATA()
    {
        unsigned mysuf  = sdata[t];
        unsigned nxtsuf = (t < 255) ? sdata[t + 1] : 0u;
        if (nxtsuf < target && mysuf >= target) { sbin[0] = (unsigned)t; sbin[1] = nxtsuf; }
    }
    __syncthreads();
    const unsigned chunkB = sbin[0];
    const unsigned gAbove = sbin[1];
    sdata[t] = (t < 4) ? AGENT_LD(&hist1[chunkB * 4 + t]) : 0u;
    SUFFIX_SCAN_SDATA()
    {
        unsigned mysuf  = sdata[t] + gAbove;
        unsigned nxtsuf = ((t < 255) ? sdata[t + 1] : 0u) + gAbove;
        if (nxtsuf < target && mysuf >= target) {
            unsigned bin = chunkB * 4 + (unsigned)t;  // hist index: 0=zeros, 1..565
            ctrl[0] = bin ? (bin + 0x3D4Bu) : 0u;     // true top-16 bits
            ctrl[1] = nxtsuf;                         // G < 100
        }
    }
}

// Kernel 2: gather candidates (one uint4 pass over keys), then the LAST block
// runs the full ranking (byte-refined) + argmax + box decode (fused k_final).
__global__ __launch_bounds__(256) void k_gather(const float* __restrict__ cls,
                                                const float* __restrict__ reg,
                                                const float* __restrict__ anc,
                                                const unsigned* __restrict__ keys,
                                                unsigned* __restrict__ ctrl,
                                                unsigned* __restrict__ candA,
                                                unsigned* __restrict__ candB,
                                                float* __restrict__ out) {
    __shared__ unsigned sAi[128], sAk[128];
    __shared__ unsigned sBi[CAPB], sBk[CAPB];
    __shared__ unsigned sdata[256];
    __shared__ unsigned sbin[2];
    __shared__ unsigned sel[TOPK];
    __shared__ int sflag;
    const int t = threadIdx.x;

    const unsigned binB = ctrl[0];               // prev kernel -> plain load ok
    const int i4 = blockIdx.x * 256 + t;
    if (i4 < A_CNT / 4) {
        uint4 k = ((const uint4*)keys)[i4];
        const unsigned base = (unsigned)(4 * i4);
#pragma unroll
        for (int j = 0; j < 4; ++j) {
            unsigned kk = (j == 0) ? k.x : (j == 1) ? k.y : (j == 2) ? k.z : k.w;
            unsigned t16 = kk >> 16;
            if (t16 > binB) {
                unsigned q = atomicAdd(&ctrl[5], 1u);
                if (q < 128u) AGENT_ST(&candA[q], base + j);
            } else if (t16 == binB) {
                unsigned q = atomicAdd(&ctrl[6], 1u);
                if (q < (unsigned)CAPB) AGENT_ST(&candB[q], base + j);
            }
        }
    }
    __syncthreads();                             // drains this thread's stores/atomics
    if (t == 0) sflag = (atomicAdd(&ctrl[9], 1u) == (unsigned)NB_GAT - 1u) ? 1 : 0;
    __syncthreads();
    if (!sflag) return;

    // ---- fused k_final (last block only) ----
    const unsigned nA = min(AGENT_LD(&ctrl[5]), 128u);   // exact G < 100
    const unsigned nB = min(AGENT_LD(&ctrl[6]), (unsigned)CAPB);
    const unsigned need = TOPK - nA;                     // >= 1; in-bin count >= need

    if (t < (int)nA) { unsigned i = AGENT_LD(&candA[t]); sAi[t] = i; sAk[t] = keys[i]; }
    for (unsigned e = (unsigned)t; e < nB; e += 256u) {
        unsigned i = AGENT_LD(&candB[e]); sBi[e] = i; sBk[e] = keys[i];
    }
    sdata[t] = 0u;
    __syncthreads();
    // byte-refinement histogram over key bits [15:8] (all candB share top16,
    // so within the bin byte order == key order).
    for (unsigned e = (unsigned)t; e < nB; e += 256u)
        atomicAdd(&sdata[(sBk[e] >> 8) & 0xFFu], 1u);
    SUFFIX_SCAN_SDATA()
    {
        unsigned mysuf  = sdata[t];
        unsigned nxtsuf = (t < 255) ? sdata[t + 1] : 0u;
        if (nxtsuf < need && mysuf >= need) { sbin[0] = (unsigned)t; sbin[1] = nxtsuf; }
    }
    __syncthreads();
    const unsigned bstar = sbin[0];              // boundary byte
    const unsigned S1    = sbin[1];              // count with byte > bstar (< need)

    if (t < (int)nA) {                           // rank strictly-above candidates
        unsigned mi = sAi[t], mk = sAk[t], r = 0;
        for (unsigned j = 0; j < nA; ++j) {
            unsigned ok = sAk[j];
            if (ok > mk || (ok == mk && sAi[j] < mi)) r++;
        }
        sel[r] = mi;
    }
    // in-bin: byte>bstar all selected (subset rank == global in-bin rank);
    // byte==bstar: best (need-S1) selected; byte<bstar: no inner scan at all.
    for (unsigned e = (unsigned)t; e < nB; e += 256u) {
        unsigned mk = sBk[e], mi = sBi[e];
        unsigned mb = (mk >> 8) & 0xFFu;
        if (mb > bstar) {
            unsigned r = 0;
            for (unsigned j = 0; j < nB; ++j) {
                unsigned ok = sBk[j];
                if (((ok >> 8) & 0xFFu) > bstar &&
                    (ok > mk || (ok == mk && sBi[j] < mi))) r++;
            }
            sel[nA + r] = mi;
        } else if (mb == bstar) {
            unsigned r = 0;
            for (unsigned j = 0; j < nB; ++j) {
                unsigned ok = sBk[j];
                if (((ok >> 8) & 0xFFu) == bstar &&
                    (ok > mk || (ok == mk && sBi[j] < mi))) r++;
            }
            if (r < need - S1) sel[nA + S1 + r] = mi;
        }
    }
    __syncthreads();

    if (t < (int)TOPK) {
        const unsigned a = sel[t];
        const float2* __restrict__ row = (const float2*)(cls + (size_t)a * C_CNT);
        float2 vr[45];
#pragma unroll
        for (int c = 0; c < 45; ++c) vr[c] = row[c]; // issue all 45 loads up front
        float bv = -INFINITY; int bi = 0;
#pragma unroll
        for (int c = 0; c < 45; ++c) {               // argmax over RAW logits (sigmoid
            if (vr[c].x > bv) { bv = vr[c].x; bi = 2 * c; }      // monotonic; strict > =
            if (vr[c].y > bv) { bv = vr[c].y; bi = 2 * c + 1; }  // first-index semantics)
        }
        float score = __uint_as_float(keys[a]);      // prob bits, or 0.0 if thresholded
        const float4 an = ((const float4*)anc)[a];
        const float4 rg = ((const float4*)reg)[a];
        float wa = an.z - an.x, ha = an.w - an.y;
        float cxa = an.x + 0.5f * wa, cya = an.y + 0.5f * ha;
        float dx = rg.x * 0.1f, dy = rg.y * 0.1f;
        float dw = rg.z * 0.2f, dh = rg.w * 0.2f;
        float cx = cxa + dx * wa, cy = cya + dy * ha;
        float w2 = expf(dw) * wa, h2 = expf(dh) * ha;
        out[t * 4 + 0] = fmaxf(cx - 0.5f * w2, 0.0f);
        out[t * 4 + 1] = fmaxf(cy - 0.5f * h2, 0.0f);
        out[t * 4 + 2] = fminf(cx + 0.5f * w2, 1024.0f);
        out[t * 4 + 3] = fminf(cy + 0.5f * h2, 1024.0f);
        out[400 + t] = score;
        out[500 + t] = (float)bi;
    }
}

extern "C" void kernel_launch(void* const* d_in, const int* in_sizes, int n_in,
                              void* d_out, int out_size, void* d_ws, size_t ws_size,
                              hipStream_t stream) {
    const float* reg = (const float*)d_in[1];
    const float* cls = (const float*)d_in[2];
    const float* anc = (const float*)d_in[3];
    float* out = (float*)d_out;
    char* ws = (char*)d_ws;
    unsigned* keys  = (unsigned*)ws;
    unsigned* hist1 = (unsigned*)(ws + OFF_HIST1);
    unsigned* ctrl  = (unsigned*)(ws + OFF_CTRL);
    unsigned* candA = (unsigned*)(ws + OFF_CANDA);
    unsigned* candB = (unsigned*)(ws + OFF_CANDB);

    // hist1 (4 KB) + ctrl (64 B, incl. done counters) are contiguous.
    hipMemsetAsync(hist1, 0, 4096 + 64, stream);
    k_reduce<<<NB_RED, 256, 0, stream>>>(cls, keys, hist1, ctrl);
    k_gather<<<NB_GAT, 256, 0, stream>>>(cls, reg, anc, keys, ctrl, candA, candB, out);
}

// Round 10
// 134.491 us; speedup vs baseline: 1.2270x; 1.1256x over previous
//
#include <hip/hip_runtime.h>
#include <cmath>

#define A_CNT 196416
#define C_CNT 90
#define QUADS (A_CNT / 4)            // 49104 quads (4 anchors = 1440 B each)
#define QITERS (QUADS / 8)           // 6138 wave-iterations (8 quads per wave-iter)
#define TOPK 100u
#define CAPB 2048
#define NB_RED 512                   // 2 blocks/CU, fully resident, 2048 waves
#define NWAVES 2048                  // grid-stride in wave-iters
#define NB_GAT 192

// ws layout (bytes):
//   [0, 785664)          keys[A]   (uint32 monotonic score keys; 0 = below threshold)
//   [785664, 789760)     hist1[1024] (coarse: idx 0 = zero-key, 1..565 = top16-0x3D4B)
//   [789760, 789824)     ctrl[16]: 0=binB(top16) 1=G 5=candA_cnt 6=candB_cnt 8=doneR 9=doneG
//   [789824, 790336)     candA[128]  (keys strictly above binB; count = G < 100)
//   [790336, 798528)     candB[2048] (keys with top16 == binB)
#define OFF_HIST1 785664u
#define OFF_CTRL  789760u
#define OFF_CANDA 789824u
#define OFF_CANDB 790336u

#define AGENT_LD(p)    __hip_atomic_load((p), __ATOMIC_RELAXED, __HIP_MEMORY_SCOPE_AGENT)
#define AGENT_ST(p, v) __hip_atomic_store((p), (v), __ATOMIC_RELAXED, __HIP_MEMORY_SCOPE_AGENT)

// ---- R15: exact revert to the session-best R7 build (133.9 us measured) ----
// R14 (R7 k_reduce + byte-refined k_gather) regressed +17.5 us; session-wide,
// every byte-refined-gather run (R9/R13/R14) landed >=151, every original-
// gather run (R7/R10/R11/R12) landed <=140.7. No clean mechanism -> per the
// post-mortem rule, the unexplained change goes. This file is byte-identical
// to the round-2 submission: rolling depth-2 source pipeline (L,L,R,L,R,R,
// 24 loads in flight, sched_barrier-pinned batches), 8 waves/CU, fused
// last-block scan; k_gather with the simple quadratic ranking.

#define LOADQ(V, qq)                                                        \
    {                                                                       \
        const float4* __restrict__ r4_ = cls4 + (size_t)(qq) * 90;          \
        _Pragma("unroll")                                                   \
        for (int i_ = 0; i_ < 12; ++i_) {                                   \
            const int j_ = s + 8 * i_;                                      \
            V[i_] = r4_[(j_ < 90) ? j_ : 89];  /* clamp dup; masked below */ \
        }                                                                   \
    }                                                                       \
    __builtin_amdgcn_sched_barrier(0);

// Quad anchors a0..a3 at float offsets 0/90/180/270 within the 360-float quad;
// straddle chunks: j=22 (88,89|90,91) and j=67 (268,269|270,271).
#define REDUCE_EMIT(V, qq)                                                  \
    {                                                                       \
        float m0 = -INFINITY, m1 = -INFINITY, m2 = -INFINITY, m3 = -INFINITY; \
        _Pragma("unroll")                                                   \
        for (int i_ = 0; i_ < 12; ++i_) {                                   \
            const int j_ = s + 8 * i_;                                      \
            const float4 vv = V[i_];                                        \
            const float a01 = fmaxf(vv.x, vv.y), a23 = fmaxf(vv.z, vv.w);   \
            const float all = fmaxf(a01, a23);                              \
            if (j_ < 22)       m0 = fmaxf(m0, all);                         \
            else if (j_ == 22) { m0 = fmaxf(m0, a01); m1 = fmaxf(m1, a23); }\
            else if (j_ < 45)  m1 = fmaxf(m1, all);                         \
            else if (j_ < 67)  m2 = fmaxf(m2, all);                         \
            else if (j_ == 67) { m2 = fmaxf(m2, a01); m3 = fmaxf(m3, a23); }\
            else if (j_ < 90)  m3 = fmaxf(m3, all);                         \
        }                                                                   \
        _Pragma("unroll")                                                   \
        for (int d_ = 1; d_ < 8; d_ <<= 1) {                                \
            m0 = fmaxf(m0, __shfl_xor(m0, d_));                             \
            m1 = fmaxf(m1, __shfl_xor(m1, d_));                             \
            m2 = fmaxf(m2, __shfl_xor(m2, d_));                             \
            m3 = fmaxf(m3, __shfl_xor(m3, d_));                             \
        }                                                                   \
        if (s == 0) {                                                       \
            float p0 = 1.0f / (1.0f + expf(-m0));   /* sigmoid(max)==max(sigmoid) */ \
            float p1 = 1.0f / (1.0f + expf(-m1));                           \
            float p2 = 1.0f / (1.0f + expf(-m2));                           \
            float p3 = 1.0f / (1.0f + expf(-m3));                           \
            unsigned k0 = (p0 > 0.05f) ? __float_as_uint(p0) : 0u;          \
            unsigned k1 = (p1 > 0.05f) ? __float_as_uint(p1) : 0u;          \
            unsigned k2 = (p2 > 0.05f) ? __float_as_uint(p2) : 0u;          \
            unsigned k3 = (p3 > 0.05f) ? __float_as_uint(p3) : 0u;          \
            *(uint4*)(keys + 4 * (size_t)(qq)) = make_uint4(k0, k1, k2, k3);\
            unsigned h0 = k0 ? (min(k0 >> 16, 0x3F80u) - 0x3D4Bu) : 0u;     \
            unsigned h1 = k1 ? (min(k1 >> 16, 0x3F80u) - 0x3D4Bu) : 0u;     \
            unsigned h2 = k2 ? (min(k2 >> 16, 0x3F80u) - 0x3D4Bu) : 0u;     \
            unsigned h3 = k3 ? (min(k3 >> 16, 0x3F80u) - 0x3D4Bu) : 0u;     \
            atomicAdd(&lhist[h0], 1u);                                      \
            atomicAdd(&lhist[h1], 1u);                                      \
            atomicAdd(&lhist[h2], 1u);                                      \
            atomicAdd(&lhist[h3], 1u);                                      \
        }                                                                   \
    }

__global__ __launch_bounds__(256, 2) void k_reduce(const float* __restrict__ cls,
                                                   unsigned* __restrict__ keys,
                                                   unsigned* __restrict__ hist1,
                                                   unsigned* __restrict__ ctrl) {
    __shared__ unsigned lhist[576];
    __shared__ unsigned sdata[256];
    __shared__ unsigned sbin[2];
    __shared__ int sflag;
    const int t = threadIdx.x;
    for (int j = t; j < 576; j += 256) lhist[j] = 0u;
    __syncthreads();

    const int lane = t & 63;
    const int g = lane >> 3, s = lane & 7;
    const int w = blockIdx.x * 4 + (t >> 6);     // wave id in [0, 2048)
    const float4* __restrict__ cls4 = (const float4*)cls;

    // wave w owns iters {w, w+2048, w+4096} ∩ [0, 6138) — exact cover of QITERS.
    const int qi0 = w;
    const int qi1 = w + NWAVES;                  // always < 6138
    const int qi2 = w + 2 * NWAVES;
    const bool has2 = (qi2 < QITERS);            // false only for 6 waves
    const int q0 = qi0 * 8 + g;
    const int q1 = qi1 * 8 + g;
    const int q2 = (has2 ? qi2 : qi0) * 8 + g;   // clamped load target; emit guarded

    float4 vA[12], vB[12];
    LOADQ(vA, q0);                               // 12 loads in flight
    LOADQ(vB, q1);                               // 24
    REDUCE_EMIT(vA, q0);                         // waits A; vB stays in flight
    LOADQ(vA, q2);                               // refill while vB lands
    REDUCE_EMIT(vB, q1);
    if (has2) REDUCE_EMIT(vA, q2);

    __syncthreads();
    for (int j = t; j < 576; j += 256) {
        unsigned c = lhist[j];
        if (c) atomicAdd(&hist1[j], c);
    }
    __syncthreads();                             // drains each thread's atomics (vmcnt)
    if (t == 0) sflag = (atomicAdd(&ctrl[8], 1u) == NB_RED - 1u) ? 1 : 0;
    __syncthreads();
    if (!sflag) return;

    // ---- fused k_scan (last block only; uniform branch, barriers legal) ----
    const unsigned target = TOPK;
    unsigned ssum = 0;
#pragma unroll
    for (int j = 0; j < 4; ++j) ssum += AGENT_LD(&hist1[t * 4 + j]);
    sdata[t] = ssum;
    for (int d = 1; d < 256; d <<= 1) {          // Hillis-Steele inclusive suffix scan
        __syncthreads();
        unsigned add = (t + d < 256) ? sdata[t + d] : 0u;
        __syncthreads();
        sdata[t] += add;
    }
    __syncthreads();
    {
        unsigned mysuf  = sdata[t];
        unsigned nxtsuf = (t < 255) ? sdata[t + 1] : 0u;
        if (nxtsuf < target && mysuf >= target) { sbin[0] = (unsigned)t; sbin[1] = nxtsuf; }
    }
    __syncthreads();
    const unsigned chunkB = sbin[0];
    const unsigned gAbove = sbin[1];
    sdata[t] = (t < 4) ? AGENT_LD(&hist1[chunkB * 4 + t]) : 0u;
    for (int d = 1; d < 256; d <<= 1) {
        __syncthreads();
        unsigned add = (t + d < 256) ? sdata[t + d] : 0u;
        __syncthreads();
        sdata[t] += add;
    }
    __syncthreads();
    {
        unsigned mysuf  = sdata[t] + gAbove;
        unsigned nxtsuf = ((t < 255) ? sdata[t + 1] : 0u) + gAbove;
        if (nxtsuf < target && mysuf >= target) {
            unsigned bin = chunkB * 4 + (unsigned)t;  // hist index: 0=zeros, 1..565
            ctrl[0] = bin ? (bin + 0x3D4Bu) : 0u;     // true top-16 bits
            ctrl[1] = nxtsuf;                         // G < 100
        }
    }
}

// Kernel 2: gather candidates (one uint4 pass over keys), then the LAST block
// runs the full ranking + argmax + box decode (fused k_final).
__global__ __launch_bounds__(256) void k_gather(const float* __restrict__ cls,
                                                const float* __restrict__ reg,
                                                const float* __restrict__ anc,
                                                const unsigned* __restrict__ keys,
                                                unsigned* __restrict__ ctrl,
                                                unsigned* __restrict__ candA,
                                                unsigned* __restrict__ candB,
                                                float* __restrict__ out) {
    __shared__ unsigned sAi[128], sAk[128];
    __shared__ unsigned sBi[CAPB], sBk[CAPB];
    __shared__ unsigned sel[TOPK];
    __shared__ int sflag;
    const int t = threadIdx.x;

    const unsigned binB = ctrl[0];               // prev kernel -> plain load ok
    const int i4 = blockIdx.x * 256 + t;
    if (i4 < A_CNT / 4) {
        uint4 k = ((const uint4*)keys)[i4];
        const unsigned base = (unsigned)(4 * i4);
#pragma unroll
        for (int j = 0; j < 4; ++j) {
            unsigned kk = (j == 0) ? k.x : (j == 1) ? k.y : (j == 2) ? k.z : k.w;
            unsigned t16 = kk >> 16;
            if (t16 > binB) {
                unsigned q = atomicAdd(&ctrl[5], 1u);
                if (q < 128u) AGENT_ST(&candA[q], base + j);
            } else if (t16 == binB) {
                unsigned q = atomicAdd(&ctrl[6], 1u);
                if (q < (unsigned)CAPB) AGENT_ST(&candB[q], base + j);
            }
        }
    }
    __syncthreads();                             // drains this thread's stores/atomics
    if (t == 0) sflag = (atomicAdd(&ctrl[9], 1u) == (unsigned)NB_GAT - 1u) ? 1 : 0;
    __syncthreads();
    if (!sflag) return;

    // ---- fused k_final (last block only) ----
    const unsigned nA = min(AGENT_LD(&ctrl[5]), 128u);   // exact G < 100
    const unsigned nB = min(AGENT_LD(&ctrl[6]), (unsigned)CAPB);
    const unsigned need = TOPK - nA;                     // >= 1; in-bin count >= need

    if (t < (int)nA) { unsigned i = AGENT_LD(&candA[t]); sAi[t] = i; sAk[t] = keys[i]; }
    for (unsigned e = (unsigned)t; e < nB; e += 256u) {
        unsigned i = AGENT_LD(&candB[e]); sBi[e] = i; sBk[e] = keys[i];
    }
    __syncthreads();

    if (t < (int)nA) {                           // rank strictly-above candidates
        unsigned mi = sAi[t], mk = sAk[t], r = 0;
        for (unsigned j = 0; j < nA; ++j) {
            unsigned ok = sAk[j];
            if (ok > mk || (ok == mk && sAi[j] < mi)) r++;
        }
        sel[r] = mi;
    }
    for (unsigned e = (unsigned)t; e < nB; e += 256u) {  // in-bin: (key desc, idx asc)
        unsigned mi = sBi[e], mk = sBk[e], r = 0;
        for (unsigned j = 0; j < nB; ++j) {
            unsigned ok = sBk[j];
            if (ok > mk || (ok == mk && sBi[j] < mi)) r++;
        }
        if (r < need) sel[nA + r] = mi;
    }
    __syncthreads();

    if (t < (int)TOPK) {
        const unsigned a = sel[t];
        const float2* __restrict__ row = (const float2*)(cls + (size_t)a * C_CNT);
        float2 vr[45];
#pragma unroll
        for (int c = 0; c < 45; ++c) vr[c] = row[c]; // issue all 45 loads up front
        float bv = -INFINITY; int bi = 0;
#pragma unroll
        for (int c = 0; c < 45; ++c) {               // argmax over RAW logits (sigmoid
            if (vr[c].x > bv) { bv = vr[c].x; bi = 2 * c; }      // monotonic; strict > =
            if (vr[c].y > bv) { bv = vr[c].y; bi = 2 * c + 1; }  // first-index semantics)
        }
        float score = __uint_as_float(keys[a]);      // prob bits, or 0.0 if thresholded
        const float4 an = ((const float4*)anc)[a];
        const float4 rg = ((const float4*)reg)[a];
        float wa = an.z - an.x, ha = an.w - an.y;
        float cxa = an.x + 0.5f * wa, cya = an.y + 0.5f * ha;
        float dx = rg.x * 0.1f, dy = rg.y * 0.1f;
        float dw = rg.z * 0.2f, dh = rg.w * 0.2f;
        float cx = cxa + dx * wa, cy = cya + dy * ha;
        float w = expf(dw) * wa, h = expf(dh) * ha;
        out[t * 4 + 0] = fmaxf(cx - 0.5f * w, 0.0f);
        out[t * 4 + 1] = fmaxf(cy - 0.5f * h, 0.0f);
        out[t * 4 + 2] = fminf(cx + 0.5f * w, 1024.0f);
        out[t * 4 + 3] = fminf(cy + 0.5f * h, 1024.0f);
        out[400 + t] = score;
        out[500 + t] = (float)bi;
    }
}

extern "C" void kernel_launch(void* const* d_in, const int* in_sizes, int n_in,
                              void* d_out, int out_size, void* d_ws, size_t ws_size,
                              hipStream_t stream) {
    const float* reg = (const float*)d_in[1];
    const float* cls = (const float*)d_in[2];
    const float* anc = (const float*)d_in[3];
    float* out = (float*)d_out;
    char* ws = (char*)d_ws;
    unsigned* keys  = (unsigned*)ws;
    unsigned* hist1 = (unsigned*)(ws + OFF_HIST1);
    unsigned* ctrl  = (unsigned*)(ws + OFF_CTRL);
    unsigned* candA = (unsigned*)(ws + OFF_CANDA);
    unsigned* candB = (unsigned*)(ws + OFF_CANDB);

    // hist1 (4 KB) + ctrl (64 B, incl. done counters) are contiguous.
    hipMemsetAsync(hist1, 0, 4096 + 64, stream);
    k_reduce<<<NB_RED, 256, 0, stream>>>(cls, keys, hist1, ctrl);
    k_gather<<<NB_GAT, 256, 0, stream>>>(cls, reg, anc, keys, ctrl, candA, candB, out);
}